// Round 12
// baseline (582.788 us; speedup 1.0000x reference)
//
#include <hip/hip_runtime.h>

#define N     4096
#define TPB   512
#define C     4
#define NCH   (N / C)
#define KB    8
#define RSZ   32
#define NW    (TPB / 64)
#define BIG   1e30f
#define YIDXf(j) ((j) + (((j) >> 4) << 2))           // padded float index
#define YIDX4(c) (((c) << 2) + (((c) >> 2) << 2))    // padded float4-chunk index

// ---------------- bidirectional triangle kernel (grid = 2) ----------------
// Block 0: forward DP on cells i+j <= 4095, captures diagonals 4094 (sA) and
// 4095 (sB). Block 1: identical DP on reversed series (== backward DP),
// captures reversed diagonals 4093 (sA -> B on 4097) and 4094 (sB -> B on
// 4096). Intra-block machinery is R11's proven diet pipeline; thread t owns
// 8 rows, runs chunk c at step s = t + 8*(t/64) + c, but only cnt(t) =
// 1024-2t chunks (triangle taper) -> makespan 1024 steps instead of 1592.
// Seam capture: after column k of an active chunk, row r matches diag KCAP
// iff e0 == r+k (e0 = KCAP - 8t - 4c), diag KCAP+1 iff e0+1 == r+k; gated on
// (unsigned)(e0+1) <= 11 so the 32-cndmask block runs ~65 steps per wave.

__global__ __launch_bounds__(TPB, 1)
void dtw_tri(const float* __restrict__ xg, const float* __restrict__ yg,
             float* __restrict__ ws) {
    __shared__ float  ylds[N + N / 4 + 4];
    __shared__ float4 bot4[2][TPB];
    __shared__ float4 ring4[NW - 1][RSZ];
    __shared__ float4 bigv;

    const int t = threadIdx.x, lane = t & 63, w = t >> 6;
    const int b = blockIdx.x;                 // 0 = fwd, 1 = bwd(reversed)
    const int KCAP = b ? 4093 : 4094;

    for (int j = t; j < N; j += TPB) {
        const int js = b ? (N - 1 - j) : j;
        ylds[YIDXf(j)] = yg[js];
    }
    if (t == 0) bigv = make_float4(BIG, BIG, BIG, BIG);

    float x[8], carry[8], sA[8], sB[8];
    const int i0 = t * 8;
#pragma unroll
    for (int r = 0; r < 8; ++r) {
        const int is = b ? (N - 1 - (i0 + r)) : (i0 + r);
        x[r] = xg[is];
        carry[r] = BIG; sA[r] = BIG; sB[r] = BIG;
    }

    float diagc = (t == 0) ? 0.0f : BIG;      // (0,0): min3(BIG,BIG,0)=0
    const int start = t + KB * w;
    const int cnt = 1024 - 2 * t;             // triangle chunks for this thread
    int e0 = KCAP - 8 * t;                    // = KCAP - i0 - 4c at c = 0

    const bool wring = (lane == 63) && (w < NW - 1);
    const int  tm1 = (t > 0) ? t - 1 : 0;

    __syncthreads();

    float4 nb4 = make_float4(BIG, BIG, BIG, BIG);
    float4 yv = *(const float4*)&ylds[0];

#define CAPK(k)                                                           \
    if ((unsigned)(e0 + 1) <= 11u) {                                      \
        _Pragma("unroll")                                                 \
        for (int r = 0; r < 8; ++r) {                                     \
            sA[r] = (e0 == r + (k)) ? carry[r] : sA[r];                   \
            sB[r] = (e0 + 1 == r + (k)) ? carry[r] : sB[r];               \
        }                                                                 \
    }

    for (int sb = 0; sb < 1024; sb += KB) {
        for (int ss = 0; ss < KB; ++ss) {
            const int s = sb + ss;
            const int c = s - start;

            if ((unsigned)c < (unsigned)cnt) {
                float bt0, bt1, bt2, bt3;
#define DO_COL(YC, NB, DG, BT)                                            \
                { float up = (NB), dgv = (DG);                            \
                  _Pragma("unroll")                                       \
                  for (int r = 0; r < 8; ++r) {                           \
                      const float old = carry[r];                         \
                      const float v = fabsf(x[r] - (YC)) +                \
                                      fminf(up, fminf(old, dgv));         \
                      carry[r] = v; up = v; dgv = old;                    \
                  }                                                       \
                  (BT) = up; }
                DO_COL(yv.x, nb4.x, diagc, bt0)
                CAPK(0)
                DO_COL(yv.y, nb4.y, nb4.x, bt1)
                CAPK(1)
                DO_COL(yv.z, nb4.z, nb4.y, bt2)
                CAPK(2)
                DO_COL(yv.w, nb4.w, nb4.z, bt3)
                CAPK(3)
#undef DO_COL
                diagc = nb4.w;
                e0 -= 4;

                float4* wp = wring ? &ring4[w][c & (RSZ - 1)]
                                   : &bot4[s & 1][t];
                *wp = make_float4(bt0, bt1, bt2, bt3);
            }

            // tail prefetch for step s+1 (unused values when inactive;
            // addresses clamped)
            {
                const int c1 = c + 1;
                const float4* rp;
                if (lane == 0)
                    rp = (w == 0) ? &bigv : &ring4[w - 1][c1 & (RSZ - 1)];
                else
                    rp = &bot4[s & 1][tm1];
                nb4 = *rp;
                int cc = c1 < 0 ? 0 : (c1 > NCH - 1 ? NCH - 1 : c1);
                yv = *(const float4*)&ylds[YIDX4(cc)];
            }
            asm volatile("" ::: "memory");
        }
        __syncthreads();
    }
#undef CAPK

    // publish seams: block b -> ws[b*8192 + {0,4096}]
    float* SA = ws + (size_t)b * 8192;
    float* SB = SA + 4096;
#pragma unroll
    for (int r = 0; r < 8; ++r) { SA[i0 + r] = sA[r]; SB[i0 + r] = sB[r]; }
}

// ---------------- seam combine (grid = 1 x 256) ----------------
// D = min_i [ F5[i] + min(B6[i], B6[i+1], B7[i+1]),  F4[i] + B6[i+1] ]
// F4 = ws[0..], F5 = ws[4096..]; B6[i] = ws[12288 + 4095-i] (bwd diag 4094),
// B7[i] = ws[8192 + 4095-i] (bwd diag 4093); i+1 terms BIG at i = 4095.
__global__ __launch_bounds__(256, 1)
void dtw_combine(const float* __restrict__ ws, float* __restrict__ out) {
    __shared__ float red[4];
    const int t = threadIdx.x;
    float m = BIG;
    for (int i = t; i < N; i += 256) {
        const float F4 = ws[i];
        const float F5 = ws[4096 + i];
        const float b6  = ws[12288 + (N - 1 - i)];
        const float b61 = (i < N - 1) ? ws[12288 + (N - 2 - i)] : BIG;
        const float b71 = (i < N - 1) ? ws[8192 + (N - 2 - i)] : BIG;
        m = fminf(m, fminf(F5 + fminf(b6, fminf(b61, b71)), F4 + b61));
    }
#pragma unroll
    for (int o = 32; o >= 1; o >>= 1) m = fminf(m, __shfl_xor(m, o));
    if ((t & 63) == 0) red[t >> 6] = m;
    __syncthreads();
    if (t == 0)
        out[0] = fminf(fminf(red[0], red[1]), fminf(red[2], red[3]));
}

// ---------------- fallback: R11 single-WG kernel (proven, 500us) ----------
__global__ __launch_bounds__(TPB, 1)
void dtw_diet(const float* __restrict__ xg, const float* __restrict__ yg,
              float* __restrict__ out) {
    __shared__ float  ylds[N + N / 4 + 4];
    __shared__ float4 bot4[2][TPB];
    __shared__ float4 ring4[NW - 1][RSZ];
    __shared__ float4 bigv;

    const int t = threadIdx.x, lane = t & 63, w = t >> 6;
    for (int j4 = t * 4; j4 < N; j4 += TPB * 4)
        *(float4*)&ylds[YIDX4(j4 >> 2)] = *(const float4*)&yg[j4];
    if (t == 0) bigv = make_float4(BIG, BIG, BIG, BIG);

    float x[8], carry[8];
    const int i0 = t * 8;
#pragma unroll
    for (int r = 0; r < 8; ++r) { x[r] = xg[i0 + r]; carry[r] = BIG; }
    float diagc = (t == 0) ? 0.0f : BIG;
    const int start = t + KB * w;
    const bool wring = (lane == 63) && (w < NW - 1);
    const int  tm1 = (t > 0) ? t - 1 : 0;
    __syncthreads();

    float4 nb4 = make_float4(BIG, BIG, BIG, BIG);
    float4 yv = *(const float4*)&ylds[0];

    for (int sb = 0; sb < 1592; sb += KB) {
        for (int ss = 0; ss < KB; ++ss) {
            const int s = sb + ss;
            const int c = s - start;
            if ((unsigned)c < (unsigned)NCH) {
                float bt0, bt1, bt2, bt3;
#define DO_COL(YC, NB, DG, BT)                                            \
                { float up = (NB), dgv = (DG);                            \
                  _Pragma("unroll")                                       \
                  for (int r = 0; r < 8; ++r) {                           \
                      const float old = carry[r];                         \
                      const float v = fabsf(x[r] - (YC)) +                \
                                      fminf(up, fminf(old, dgv));         \
                      carry[r] = v; up = v; dgv = old;                    \
                  }                                                       \
                  (BT) = up; }
                DO_COL(yv.x, nb4.x, diagc, bt0)
                DO_COL(yv.y, nb4.y, nb4.x, bt1)
                DO_COL(yv.z, nb4.z, nb4.y, bt2)
                DO_COL(yv.w, nb4.w, nb4.z, bt3)
#undef DO_COL
                diagc = nb4.w;
                float4* wp = wring ? &ring4[w][c & (RSZ - 1)]
                                   : &bot4[s & 1][t];
                *wp = make_float4(bt0, bt1, bt2, bt3);
            }
            {
                const int c1 = c + 1;
                const float4* rp;
                if (lane == 0)
                    rp = (w == 0) ? &bigv : &ring4[w - 1][c1 & (RSZ - 1)];
                else
                    rp = &bot4[s & 1][tm1];
                nb4 = *rp;
                int cc = c1 < 0 ? 0 : (c1 > NCH - 1 ? NCH - 1 : c1);
                yv = *(const float4*)&ylds[YIDX4(cc)];
            }
            asm volatile("" ::: "memory");
        }
        __syncthreads();
    }
    if (t == TPB - 1) out[0] = carry[7];
}

extern "C" void kernel_launch(void* const* d_in, const int* in_sizes, int n_in,
                              void* d_out, int out_size, void* d_ws, size_t ws_size,
                              hipStream_t stream) {
    const float* src = (const float*)d_in[0];
    const float* tgt = (const float*)d_in[1];
    float* out = (float*)d_out;

    if (ws_size >= 4 * 4096 * sizeof(float)) {
        float* ws = (float*)d_ws;
        hipLaunchKernelGGL(dtw_tri, dim3(2), dim3(TPB), 0, stream, src, tgt, ws);
        hipLaunchKernelGGL(dtw_combine, dim3(1), dim3(256), 0, stream, ws, out);
    } else {
        hipLaunchKernelGGL(dtw_diet, dim3(1), dim3(TPB), 0, stream,
                           src, tgt, out);
    }
}

// Round 13
// 360.743 us; speedup vs baseline: 1.6155x; 1.6155x over previous
//
#include <hip/hip_runtime.h>

#define N     4096
#define TPB   512
#define C     4
#define KB    8
#define RSZ   32
#define NW    (TPB / 64)
#define BIG   1e30f
#define YIDXf(j) ((j) + (((j) >> 4) << 2))           // padded float index
#define YIDX4(c) (((c) << 2) + (((c) >> 2) << 2))    // padded float4-chunk index

// ---------------- bidirectional column-seam kernel (grid = 2) ----------------
// Block 0: forward DP on the left half (cols 0..2047) of the full 4096-row
// matrix; block 1: the same DP on (x reversed, y reversed), whose column-2047
// vector equals the backward costs B[:, 2048] reversed. Both halves are
// DP-closed (column j depends only on j-1), so each is bit-exact. Every
// thread has an identical 512-chunk workload -> balanced, 2 waves/SIMD busy
// throughout (fixes R12's taper imbalance). Machinery = R11's proven diet
// pipeline. Capture is free: after a thread's last chunk, carry[] holds its
// 8 values of column 2047; publish to ws after the loop.

#define NCHH   512            // 2048 cols / C
#define STEPSH 1080           // last active step 567+511=1078, rounded to KB

__global__ __launch_bounds__(TPB, 1)
void dtw_half(const float* __restrict__ xg, const float* __restrict__ yg,
              float* __restrict__ ws) {
    __shared__ float  ylds[2048 + 2048 / 4 + 4];   // 10 KB
    __shared__ float4 bot4[2][TPB];                // 16 KB
    __shared__ float4 ring4[NW - 1][RSZ];          // 3.5 KB
    __shared__ float4 bigv;

    const int t = threadIdx.x, lane = t & 63, w = t >> 6;
    const int b = blockIdx.x;                      // 0 = fwd, 1 = bwd(reversed)

    for (int j = t; j < 2048; j += TPB)
        ylds[YIDXf(j)] = b ? yg[N - 1 - j] : yg[j];
    if (t == 0) bigv = make_float4(BIG, BIG, BIG, BIG);

    float x[8], carry[8];
    const int i0 = t * 8;
#pragma unroll
    for (int r = 0; r < 8; ++r) {
        x[r] = b ? xg[N - 1 - (i0 + r)] : xg[i0 + r];
        carry[r] = BIG;
    }

    float diagc = (t == 0) ? 0.0f : BIG;   // (0,0): min3(BIG,BIG,0)=0 -> D[0][0]=c
    const int start = t + KB * w;
    const bool wring = (lane == 63) && (w < NW - 1);
    const int  tm1 = (t > 0) ? t - 1 : 0;

    __syncthreads();

    float4 nb4 = make_float4(BIG, BIG, BIG, BIG);
    float4 yv = *(const float4*)&ylds[0];

    for (int sb = 0; sb < STEPSH; sb += KB) {
        for (int ss = 0; ss < KB; ++ss) {
            const int s = sb + ss;
            const int c = s - start;

            if ((unsigned)c < (unsigned)NCHH) {
                float bt0, bt1, bt2, bt3;
#define DO_COL(YC, NB, DG, BT)                                            \
                { float up = (NB), dgv = (DG);                            \
                  _Pragma("unroll")                                       \
                  for (int r = 0; r < 8; ++r) {                           \
                      const float old = carry[r];                         \
                      const float v = fabsf(x[r] - (YC)) +                \
                                      fminf(up, fminf(old, dgv));         \
                      carry[r] = v; up = v; dgv = old;                    \
                  }                                                       \
                  (BT) = up; }
                DO_COL(yv.x, nb4.x, diagc, bt0)
                DO_COL(yv.y, nb4.y, nb4.x, bt1)
                DO_COL(yv.z, nb4.z, nb4.y, bt2)
                DO_COL(yv.w, nb4.w, nb4.z, bt3)
#undef DO_COL
                diagc = nb4.w;

                float4* wp = wring ? &ring4[w][c & (RSZ - 1)]
                                   : &bot4[s & 1][t];
                *wp = make_float4(bt0, bt1, bt2, bt3);
            }

            // tail prefetch for step s+1 (values unused when inactive;
            // addresses clamped)
            {
                const int c1 = c + 1;
                const float4* rp;
                if (lane == 0)
                    rp = (w == 0) ? &bigv : &ring4[w - 1][c1 & (RSZ - 1)];
                else
                    rp = &bot4[s & 1][tm1];
                nb4 = *rp;
                int cc = c1 < 0 ? 0 : (c1 > NCHH - 1 ? NCHH - 1 : c1);
                yv = *(const float4*)&ylds[YIDX4(cc)];
            }
            asm volatile("" ::: "memory");
        }
        __syncthreads();
    }

    // publish column-2047 slice: carry[] survived untouched since last chunk
    float* dst = ws + (size_t)b * 4096;
#pragma unroll
    for (int r = 0; r < 8; ++r) dst[i0 + r] = carry[r];
}

// ---------------- seam combine (grid = 1 x 256) ----------------
// D = min_i [ F[i] + min(B[i], B[i+1]) ], F = ws[0..4095],
// B[i] = Brev[4095-i] with Brev = ws[4096..8191]; B[4096] = BIG.
__global__ __launch_bounds__(256, 1)
void dtw_combine(const float* __restrict__ ws, float* __restrict__ out) {
    __shared__ float red[4];
    const int t = threadIdx.x;
    float m = BIG;
    for (int i = t; i < N; i += 256) {
        const float F  = ws[i];
        const float B0 = ws[4096 + (N - 1 - i)];
        const float B1 = (i < N - 1) ? ws[4096 + (N - 2 - i)] : BIG;
        m = fminf(m, F + fminf(B0, B1));
    }
#pragma unroll
    for (int o = 32; o >= 1; o >>= 1) m = fminf(m, __shfl_xor(m, o));
    if ((t & 63) == 0) red[t >> 6] = m;
    __syncthreads();
    if (t == 0)
        out[0] = fminf(fminf(red[0], red[1]), fminf(red[2], red[3]));
}

// ---------------- fallback: R11 single-WG kernel (proven, 500us) ----------
#define NCH (N / C)
__global__ __launch_bounds__(TPB, 1)
void dtw_diet(const float* __restrict__ xg, const float* __restrict__ yg,
              float* __restrict__ out) {
    __shared__ float  ylds[N + N / 4 + 4];
    __shared__ float4 bot4[2][TPB];
    __shared__ float4 ring4[NW - 1][RSZ];
    __shared__ float4 bigv;

    const int t = threadIdx.x, lane = t & 63, w = t >> 6;
    for (int j4 = t * 4; j4 < N; j4 += TPB * 4)
        *(float4*)&ylds[YIDX4(j4 >> 2)] = *(const float4*)&yg[j4];
    if (t == 0) bigv = make_float4(BIG, BIG, BIG, BIG);

    float x[8], carry[8];
    const int i0 = t * 8;
#pragma unroll
    for (int r = 0; r < 8; ++r) { x[r] = xg[i0 + r]; carry[r] = BIG; }
    float diagc = (t == 0) ? 0.0f : BIG;
    const int start = t + KB * w;
    const bool wring = (lane == 63) && (w < NW - 1);
    const int  tm1 = (t > 0) ? t - 1 : 0;
    __syncthreads();

    float4 nb4 = make_float4(BIG, BIG, BIG, BIG);
    float4 yv = *(const float4*)&ylds[0];

    for (int sb = 0; sb < 1592; sb += KB) {
        for (int ss = 0; ss < KB; ++ss) {
            const int s = sb + ss;
            const int c = s - start;
            if ((unsigned)c < (unsigned)NCH) {
                float bt0, bt1, bt2, bt3;
#define DO_COL(YC, NB, DG, BT)                                            \
                { float up = (NB), dgv = (DG);                            \
                  _Pragma("unroll")                                       \
                  for (int r = 0; r < 8; ++r) {                           \
                      const float old = carry[r];                         \
                      const float v = fabsf(x[r] - (YC)) +                \
                                      fminf(up, fminf(old, dgv));         \
                      carry[r] = v; up = v; dgv = old;                    \
                  }                                                       \
                  (BT) = up; }
                DO_COL(yv.x, nb4.x, diagc, bt0)
                DO_COL(yv.y, nb4.y, nb4.x, bt1)
                DO_COL(yv.z, nb4.z, nb4.y, bt2)
                DO_COL(yv.w, nb4.w, nb4.z, bt3)
#undef DO_COL
                diagc = nb4.w;
                float4* wp = wring ? &ring4[w][c & (RSZ - 1)]
                                   : &bot4[s & 1][t];
                *wp = make_float4(bt0, bt1, bt2, bt3);
            }
            {
                const int c1 = c + 1;
                const float4* rp;
                if (lane == 0)
                    rp = (w == 0) ? &bigv : &ring4[w - 1][c1 & (RSZ - 1)];
                else
                    rp = &bot4[s & 1][tm1];
                nb4 = *rp;
                int cc = c1 < 0 ? 0 : (c1 > NCH - 1 ? NCH - 1 : c1);
                yv = *(const float4*)&ylds[YIDX4(cc)];
            }
            asm volatile("" ::: "memory");
        }
        __syncthreads();
    }
    if (t == TPB - 1) out[0] = carry[7];
}

extern "C" void kernel_launch(void* const* d_in, const int* in_sizes, int n_in,
                              void* d_out, int out_size, void* d_ws, size_t ws_size,
                              hipStream_t stream) {
    const float* src = (const float*)d_in[0];
    const float* tgt = (const float*)d_in[1];
    float* out = (float*)d_out;

    if (ws_size >= 2 * 4096 * sizeof(float)) {
        float* ws = (float*)d_ws;
        hipLaunchKernelGGL(dtw_half, dim3(2), dim3(TPB), 0, stream, src, tgt, ws);
        hipLaunchKernelGGL(dtw_combine, dim3(1), dim3(256), 0, stream, ws, out);
    } else {
        hipLaunchKernelGGL(dtw_diet, dim3(1), dim3(TPB), 0, stream,
                           src, tgt, out);
    }
}